// Round 13
// baseline (29054.675 us; speedup 1.0000x reference)
//
#include <hip/hip_runtime.h>
#include <cstdint>
#include <cstddef>

#define TT 512
#define DZP 65                              // dz row stride (doubles), conflict-free

// ---- ws layout (float offsets) ----  total 5456896 floats = 21.8 MB
#define O_BAR   0                           // 1024 barrier words (zeroed by prep)
#define O_HT    1024                        // [3 layer][2 parity] hq[128 kq][64 m][4 q]
#define WS_ZERO (O_HT + 6*32768)            // prep zeroes [0, WS_ZERO)
#define O_CWP0  WS_ZERO                     // [256 p][512 k][8 j]   U0 packed
#define O_CWP1  (O_CWP0 + 256*512*8)        // [256 p][1024 k][8 j]  [W1;U1] packed
#define O_CWP2  (O_CWP1 + 256*1024*8)       // [256 p][1024 k][8 j]  [W2;U2] packed
#define O_W0P   (O_CWP2 + 256*1024*8)       // [256 p][8 e][8 j]     W0 packed
#define WS_ALL  (O_W0P + 256*64)

#define BARR(g) (64 + (g) * 16)
#define BGRP    32
#define BREL(g) (512 + (g) * 16)

typedef float f4v __attribute__((ext_vector_type(4)));

// Coherent (cross-XCD) ops: plain global instrs with sc0+sc1 — bypass stale
// L1/L2, batchable; counted per-wave by vmcnt.
__device__ __forceinline__ void coh_ld16(f4v* dst, const f4v* addr) {
  asm volatile("global_load_dwordx4 %0, %1, off sc0 sc1" : "=v"(*dst) : "v"(addr));
}
__device__ __forceinline__ void coh_st4(float* addr, float v) {
  asm volatile("global_store_dword %0, %1, off sc0 sc1" :: "v"(addr), "v"(v) : "memory");
}
// counted wait + sched fence (rule #18)
#define VMWAIT(n) do { asm volatile("s_waitcnt vmcnt(" #n ")" ::: "memory"); \
                       __builtin_amdgcn_sched_barrier(0); } while (0)
// phase barrier: LDS-only drain + raw s_barrier — NO vmcnt drain, so h-load
// prefetches stay in flight across phase boundaries (the key fix this round)
#define LGKMBAR() do { asm volatile("s_waitcnt lgkmcnt(0)\n\ts_barrier" ::: "memory"); } while (0)

__device__ __forceinline__ void issue8(f4v h[8], const f4v* hq, int kq0, int lane) {
  const f4v* base = hq + (size_t)kq0 * 64 + lane;
#pragma unroll
  for (int i = 0; i < 8; ++i) coh_ld16(&h[i], base + i * 64);
}

// one 32-k chunk: f32 fma chain per gate col, one f64 flush (order = r12)
__device__ __forceinline__ void comp8(const f4v h[8], const float* wk, double d[8]) {
  float s8[8] = {0.f, 0.f, 0.f, 0.f, 0.f, 0.f, 0.f, 0.f};
#pragma unroll
  for (int i = 0; i < 8; ++i) {
#pragma unroll
    for (int q = 0; q < 4; ++q) {
      const float xk = h[i][q];
      const float4 wa = *(const float4*)&wk[(i * 4 + q) * 8];      // LDS bcast
      const float4 wb = *(const float4*)&wk[(i * 4 + q) * 8 + 4];
      s8[0] = fmaf(xk, wa.x, s8[0]); s8[1] = fmaf(xk, wa.y, s8[1]);
      s8[2] = fmaf(xk, wa.z, s8[2]); s8[3] = fmaf(xk, wa.w, s8[3]);
      s8[4] = fmaf(xk, wb.x, s8[4]); s8[5] = fmaf(xk, wb.y, s8[5]);
      s8[6] = fmaf(xk, wb.z, s8[6]); s8[7] = fmaf(xk, wb.w, s8[7]);
    }
  }
#pragma unroll
  for (int j = 0; j < 8; ++j) d[j] += (double)s8[j];
}

// epilogue: every wave handles 16 outputs (lanes 0-15) => exactly ONE
// coherent store issues per wave -> wave-uniform vmcnt sequence.
__device__ __forceinline__ void epilogue(
    double* dz, const float br[4], float* creg, float* hdstT,
    int p, int w, int lane)
{
  if (lane < 16) {
    const int uu = w >> 2;
    const int em = (w & 3) * 16 + lane;
    float zf[4];
#pragma unroll
    for (int g = 0; g < 4; ++g) {
      double zs = (double)br[g];
#pragma unroll
      for (int w8 = 0; w8 < 8; ++w8)
        zs += dz[((g * 2 + uu) * 8 + w8) * DZP + em];
      zf[g] = (float)zs;
    }
    const float iv = 1.f / (1.f + expf(-zf[0]));
    const float fv = 1.f / (1.f + expf(-zf[1]));
    const float gv = tanhf(zf[2]);
    const float ov = 1.f / (1.f + expf(-zf[3]));
    const float cn = fv * (*creg) + iv * gv;
    *creg = cn;
    const int u = 2 * p + uu;
    coh_st4(&hdstT[((u >> 2) * 64 + em) * 4 + (u & 3)], ov * tanhf(cn));
  }
}

__device__ __forceinline__ void grid_barrier(unsigned* bar, unsigned target, int tid, int bid) {
  __syncthreads();          // compiler drains vmcnt(0) per wave (h stores!)
  if (tid == 0) {
    asm volatile("s_waitcnt vmcnt(0)" ::: "memory");
    const unsigned g = (unsigned)bid & 15u;
    const unsigned o = atomicAdd(&bar[BARR(g)], 1u);
    if ((o & 15u) == 15u) {
      const unsigned o2 = atomicAdd(&bar[BGRP], 1u);
      if ((o2 & 15u) == 15u) {
#pragma unroll
        for (int q = 0; q < 16; ++q) atomicExch(&bar[BREL(q)], target);
      }
    }
    unsigned spins = 0;
    while (atomicAdd(&bar[BREL(g)], 0u) != target) {
      if (++spins > 30000u) break;
      __builtin_amdgcn_s_sleep(2);
    }
  }
  __syncthreads();
}

__global__ void __launch_bounds__(256)
rnn_prep(float* __restrict__ ws,
         const float* __restrict__ W0, const float* __restrict__ U0,
         const float* __restrict__ W1, const float* __restrict__ U1,
         const float* __restrict__ W2, const float* __restrict__ U2)
{
  const int tid = (int)threadIdx.x;
  const int bid = (int)blockIdx.x;
  const int gtid = bid * 256 + tid;
  for (int i = gtid; i < WS_ZERO; i += 768 * 256) ws[i] = 0.f;

  float* CWP0 = ws + O_CWP0;
  float* CWP1 = ws + O_CWP1;
  float* CWP2 = ws + O_CWP2;
  float* W0P  = ws + O_W0P;
  if (bid < 256) {
    const int p = bid;
    for (int k = tid; k < 512; k += 256)
#pragma unroll
      for (int j = 0; j < 8; ++j) {
        const int col = ((j >> 1) << 9) + 2 * p + (j & 1);
        CWP0[((size_t)p * 512 + k) * 8 + j] = U0[(size_t)k * 2048 + col];
      }
    if (tid < 64) {
      const int e = tid >> 3, j = tid & 7;
      const int col = ((j >> 1) << 9) + 2 * p + (j & 1);
      W0P[p * 64 + e * 8 + j] = W0[(size_t)e * 2048 + col];
    }
  } else if (bid < 512) {
    const int p = bid - 256;
    for (int k = tid; k < 1024; k += 256) {
      const float* src = (k < 512) ? &W1[(size_t)k * 2048] : &U1[(size_t)(k - 512) * 2048];
#pragma unroll
      for (int j = 0; j < 8; ++j) {
        const int col = ((j >> 1) << 9) + 2 * p + (j & 1);
        CWP1[((size_t)p * 1024 + k) * 8 + j] = src[col];
      }
    }
  } else {
    const int p = bid - 512;
    for (int k = tid; k < 1024; k += 256) {
      const float* src = (k < 512) ? &W2[(size_t)k * 2048] : &U2[(size_t)(k - 512) * 2048];
#pragma unroll
      for (int j = 0; j < 8; ++j) {
        const int col = ((j >> 1) << 9) + 2 * p + (j & 1);
        CWP2[((size_t)p * 1024 + k) * 8 + j] = src[col];
      }
    }
  }
}

__global__ void __launch_bounds__(512, 2)
rnn_all(const int* __restrict__ tokens, const float* __restrict__ emb,
        const float* __restrict__ b0, const float* __restrict__ b1,
        const float* __restrict__ b2,
        const float* __restrict__ Wd, const float* __restrict__ bd,
        float* __restrict__ out, float* __restrict__ ws)
{
  __shared__ __align__(16) float wl[20544];    // 80.25 KiB weight slice
  __shared__ double dz[64 * DZP];              // 33.3 KiB partials (padded)
  __shared__ float red[512];                   // 2 KiB softmax reduce
  const int tid = (int)threadIdx.x;
  const int p = (int)blockIdx.x;               // unit pair
  const int lane = tid & 63;
  const int w = __builtin_amdgcn_readfirstlane(tid >> 6);
  unsigned* bar = (unsigned*)ws;
  float* ht = ws + O_HT;

  { // one-time LDS weight load
    const float* s0 = ws + O_CWP0 + (size_t)p * 4096;
    for (int i = tid; i < 4096; i += 512) wl[i] = s0[i];
    const float* s1 = ws + O_CWP1 + (size_t)p * 8192;
    for (int i = tid; i < 8192; i += 512) wl[4096 + i] = s1[i];
    const float* s2 = ws + O_CWP2 + (size_t)p * 8192;
    for (int i = tid; i < 8192; i += 512) wl[12288 + i] = s2[i];
    if (tid < 64) wl[20480 + tid] = ws[O_W0P + p * 64 + tid];
  }
  // per-thread epilogue bias registers (keeps vector loads out of the pipeline)
  float br0[4], br1[4], br2[4];
  {
    const int uu = w >> 2;
#pragma unroll
    for (int g = 0; g < 4; ++g) {
      const int c_ = (g << 9) + 2 * p + uu;
      br0[g] = b0[c_]; br1[g] = b1[c_]; br2[g] = b2[c_];
    }
  }
  float c0 = 0.f, c1 = 0.f, c2 = 0.f;
  __syncthreads();

  for (int s = 0; s < 515; ++s) {
    const int po = (s + 1) & 1;
    const int pw = s & 1;
    float* h0po = ht + (size_t)(0 * 2 + po) * 32768;
    float* h1po = ht + (size_t)(1 * 2 + po) * 32768;
    float* h2po = ht + (size_t)(2 * 2 + po) * 32768;
    float* h0pw = ht + (size_t)(0 * 2 + pw) * 32768;
    float* h1pw = ht + (size_t)(1 * 2 + pw) * 32768;
    float* h2pw = ht + (size_t)(2 * 2 + pw) * 32768;

    // per-wave source pointers / k bases (h stable all step: parity po)
    const f4v* hqL0 = (const f4v*)h0po;  const int kqA = w * 16;
    const f4v* hqL1 = (w < 4) ? (const f4v*)h0po : (const f4v*)h1po;
    const f4v* hqL2 = (w < 4) ? (const f4v*)h1po : (const f4v*)h2po;
    const int kqC = (w & 3) * 32;
    const float* wkL0 = wl + (size_t)(w * 64) * 8;
    const float* wkL1 = wl + 4096 + (size_t)(w * 128) * 8;
    const float* wkL2 = wl + 12288 + (size_t)(w * 128) * 8;

    double d[8] = {0, 0, 0, 0, 0, 0, 0, 0};
    // embedding partial first (wave 0) -- compiler-tracked loads complete
    // BEFORE the asm pipeline starts, so no stray vmcnt drains inside it
    if (s < 512 && w == 0) {
      const int tok = tokens[lane * TT + s];
      const float4 e0 = *(const float4*)&emb[tok * 8];
      const float4 e1 = *(const float4*)&emb[tok * 8 + 4];
      float s8[8] = {0.f, 0.f, 0.f, 0.f, 0.f, 0.f, 0.f, 0.f};
#pragma unroll
      for (int e = 0; e < 8; ++e) {
        const float xe = (e < 4) ? ((const float*)&e0)[e] : ((const float*)&e1)[e - 4];
        const float4 wa = *(const float4*)&wl[20480 + e * 8];
        const float4 wb = *(const float4*)&wl[20480 + e * 8 + 4];
        s8[0] = fmaf(xe, wa.x, s8[0]); s8[1] = fmaf(xe, wa.y, s8[1]);
        s8[2] = fmaf(xe, wa.z, s8[2]); s8[3] = fmaf(xe, wa.w, s8[3]);
        s8[4] = fmaf(xe, wb.x, s8[4]); s8[5] = fmaf(xe, wb.y, s8[5]);
        s8[6] = fmaf(xe, wb.z, s8[6]); s8[7] = fmaf(xe, wb.w, s8[7]);
      }
#pragma unroll
      for (int j = 0; j < 8; ++j) d[j] += (double)s8[j];
    }

    f4v bA[8], bB[8], bC[8];                    // 3 rotating chunk buffers

#define DZFLUSH() do { _Pragma("unroll") \
    for (int j = 0; j < 8; ++j) { dz[(j * 8 + w) * DZP + lane] = d[j]; d[j] = 0.0; } } while (0)

    if (s >= 2 && s < 512) {                    // ---- fast path: full pipeline
      issue8(bA, hqL0, kqA, lane);              // A
      issue8(bB, hqL0, kqA + 8, lane);          // B
      issue8(bC, hqL1, kqC, lane);              // C
      VMWAIT(16); comp8(bA, wkL0, d);           // A
      issue8(bA, hqL1, kqC + 8, lane);          // D
      VMWAIT(16); comp8(bB, wkL0 + 256, d);     // B
      DZFLUSH(); LGKMBAR();
      epilogue(dz, br0, &c0, h0pw, p, w, lane); LGKMBAR();   // store s0
      issue8(bB, hqL1, kqC + 16, lane);         // E
      VMWAIT(17); comp8(bC, wkL1, d);           // C
      issue8(bC, hqL1, kqC + 24, lane);         // F
      VMWAIT(17); comp8(bA, wkL1 + 256, d);     // D
      issue8(bA, hqL2, kqC, lane);              // G
      VMWAIT(16); comp8(bB, wkL1 + 512, d);     // E
      issue8(bB, hqL2, kqC + 8, lane);          // H
      VMWAIT(16); comp8(bC, wkL1 + 768, d);     // F
      DZFLUSH(); LGKMBAR();
      epilogue(dz, br1, &c1, h1pw, p, w, lane); LGKMBAR();   // store s1
      issue8(bC, hqL2, kqC + 16, lane);         // I
      VMWAIT(17); comp8(bA, wkL2, d);           // G
      issue8(bA, hqL2, kqC + 24, lane);         // J
      VMWAIT(17); comp8(bB, wkL2 + 256, d);     // H
      VMWAIT(8);  comp8(bC, wkL2 + 512, d);     // I
      VMWAIT(0);  comp8(bA, wkL2 + 768, d);     // J
      DZFLUSH(); LGKMBAR();
      epilogue(dz, br2, &c2, h2pw, p, w, lane); LGKMBAR();   // store s2
    } else {                                    // ---- boundary steps: simple
      if (s < 512) {
        issue8(bA, hqL0, kqA, lane); issue8(bB, hqL0, kqA + 8, lane);
        VMWAIT(0); comp8(bA, wkL0, d); comp8(bB, wkL0 + 256, d);
        DZFLUSH(); LGKMBAR();
        epilogue(dz, br0, &c0, h0pw, p, w, lane); LGKMBAR();
      }
      if (s >= 1 && s < 513) {
        issue8(bA, hqL1, kqC, lane);      issue8(bB, hqL1, kqC + 8, lane);
        VMWAIT(8); comp8(bA, wkL1, d);
        issue8(bC, hqL1, kqC + 16, lane); VMWAIT(8); comp8(bB, wkL1 + 256, d);
        issue8(bA, hqL1, kqC + 24, lane); VMWAIT(8); comp8(bC, wkL1 + 512, d);
        VMWAIT(0); comp8(bA, wkL1 + 768, d);
        DZFLUSH(); LGKMBAR();
        epilogue(dz, br1, &c1, h1pw, p, w, lane); LGKMBAR();
      }
      if (s >= 2 && s < 514) {
        issue8(bA, hqL2, kqC, lane);      issue8(bB, hqL2, kqC + 8, lane);
        VMWAIT(8); comp8(bA, wkL2, d);
        issue8(bC, hqL2, kqC + 16, lane); VMWAIT(8); comp8(bB, wkL2 + 256, d);
        issue8(bA, hqL2, kqC + 24, lane); VMWAIT(8); comp8(bC, wkL2 + 512, d);
        VMWAIT(0); comp8(bA, wkL2 + 768, d);
        DZFLUSH(); LGKMBAR();
        epilogue(dz, br2, &c2, h2pw, p, w, lane); LGKMBAR();
      }
    }

    if (s >= 3 && p < 64) {                     // FIN: logits+softmax, t=s-3
      const int r = p;
      const f4v* h2q = (const f4v*)h2po;
      const int col = tid & 127, kq4 = tid >> 7;
      f4v fa[8], fb[8], fc[8], fd[8];
#pragma unroll
      for (int i = 0; i < 8; ++i) coh_ld16(&fa[i], h2q + (size_t)(kq4 * 32 + i) * 64 + r);
#pragma unroll
      for (int i = 0; i < 8; ++i) coh_ld16(&fb[i], h2q + (size_t)(kq4 * 32 + 8 + i) * 64 + r);
#pragma unroll
      for (int i = 0; i < 8; ++i) coh_ld16(&fc[i], h2q + (size_t)(kq4 * 32 + 16 + i) * 64 + r);
#pragma unroll
      for (int i = 0; i < 8; ++i) coh_ld16(&fd[i], h2q + (size_t)(kq4 * 32 + 24 + i) * 64 + r);
      VMWAIT(0);
      double acc = 0.0;
#pragma unroll
      for (int ch = 0; ch < 4; ++ch) {
        const f4v* f_ = (ch == 0) ? fa : (ch == 1) ? fb : (ch == 2) ? fc : fd;
        float sa = 0.f;
#pragma unroll
        for (int i = 0; i < 8; ++i)
#pragma unroll
          for (int q = 0; q < 4; ++q) {
            const int k = (kq4 * 32 + ch * 8 + i) * 4 + q;
            sa = fmaf(f_[i][q], Wd[(size_t)k * 128 + col], sa);
          }
        acc += (double)sa;
      }
      dz[tid] = acc;
      __syncthreads();
      float xlg = -3.0e38f;
      if (tid < 128)
        xlg = (float)(dz[tid] + dz[tid + 128] + dz[tid + 256] + dz[tid + 384]
                      + (double)bd[col]);
      red[tid] = xlg;                       __syncthreads();
      if (tid < 256) red[tid] = fmaxf(red[tid], red[tid + 256]); __syncthreads();
      if (tid < 128) red[tid] = fmaxf(red[tid], red[tid + 128]); __syncthreads();
      if (tid < 64)  red[tid] = fmaxf(red[tid], red[tid + 64]);  __syncthreads();
      if (tid < 32)  red[tid] = fmaxf(red[tid], red[tid + 32]);  __syncthreads();
      if (tid < 16)  red[tid] = fmaxf(red[tid], red[tid + 16]);  __syncthreads();
      if (tid < 8)   red[tid] = fmaxf(red[tid], red[tid + 8]);   __syncthreads();
      if (tid < 4)   red[tid] = fmaxf(red[tid], red[tid + 4]);   __syncthreads();
      if (tid < 2)   red[tid] = fmaxf(red[tid], red[tid + 2]);   __syncthreads();
      if (tid < 1)   red[tid] = fmaxf(red[tid], red[tid + 1]);   __syncthreads();
      const float mx = red[0];              __syncthreads();
      const float ex = (tid < 128) ? expf(xlg - mx) : 0.f;
      red[tid] = ex;                        __syncthreads();
      if (tid < 256) red[tid] += red[tid + 256]; __syncthreads();
      if (tid < 128) red[tid] += red[tid + 128]; __syncthreads();
      if (tid < 64)  red[tid] += red[tid + 64];  __syncthreads();
      if (tid < 32)  red[tid] += red[tid + 32];  __syncthreads();
      if (tid < 16)  red[tid] += red[tid + 16];  __syncthreads();
      if (tid < 8)   red[tid] += red[tid + 8];   __syncthreads();
      if (tid < 4)   red[tid] += red[tid + 4];   __syncthreads();
      if (tid < 2)   red[tid] += red[tid + 2];   __syncthreads();
      if (tid < 1)   red[tid] += red[tid + 1];   __syncthreads();
      const float inv = 1.f / red[0];
      if (tid < 128) out[((size_t)r * 512 + (s - 3)) * 128 + tid] = ex * inv;
    }

    grid_barrier(bar, (unsigned)(s + 1), tid, p);
  }
}

extern "C" void kernel_launch(void* const* d_in, const int* in_sizes, int n_in,
                              void* d_out, int out_size, void* d_ws, size_t ws_size,
                              hipStream_t stream) {
  (void)in_sizes; (void)n_in; (void)out_size;
  if (ws_size < (size_t)WS_ALL * 4) return;
  const int*   tokens = (const int*)d_in[0];
  const float* emb = (const float*)d_in[1];
  const float* W0 = (const float*)d_in[2];
  const float* U0 = (const float*)d_in[3];
  const float* b0 = (const float*)d_in[4];
  const float* W1 = (const float*)d_in[5];
  const float* U1 = (const float*)d_in[6];
  const float* b1 = (const float*)d_in[7];
  const float* W2 = (const float*)d_in[8];
  const float* U2 = (const float*)d_in[9];
  const float* b2 = (const float*)d_in[10];
  const float* Wd = (const float*)d_in[11];
  const float* bd = (const float*)d_in[12];
  float* out = (float*)d_out;
  float* ws  = (float*)d_ws;

  hipLaunchKernelGGL(rnn_prep, dim3(768), dim3(256), 0, stream,
                     ws, W0, U0, W1, U1, W2, U2);
  hipLaunchKernelGGL(rnn_all, dim3(256), dim3(512), 0, stream,
                     tokens, emb, b0, b1, b2, Wd, bd, out, ws);
}

// Round 14
// 21978.300 us; speedup vs baseline: 1.3220x; 1.3220x over previous
//
#include <hip/hip_runtime.h>
#include <cstdint>
#include <cstddef>

#define TT 512
#define DZP 65                              // dz row stride (doubles), conflict-free

// ---- ws layout (float offsets) ----  total 5456896 floats = 21.8 MB
#define O_BAR   0                           // 1024 barrier words (zeroed by prep)
#define O_HT    1024                        // [3 layer][2 parity] hq[128 kq][64 m][4 q]
#define WS_ZERO (O_HT + 6*32768)            // prep zeroes [0, WS_ZERO)
#define O_CWP0  WS_ZERO                     // [256 p][512 k][8 j]   U0 packed
#define O_CWP1  (O_CWP0 + 256*512*8)        // [256 p][1024 k][8 j]  [W1;U1] packed
#define O_CWP2  (O_CWP1 + 256*1024*8)       // [256 p][1024 k][8 j]  [W2;U2] packed
#define O_W0P   (O_CWP2 + 256*1024*8)       // [256 p][8 e][8 j]     W0 packed
#define WS_ALL  (O_W0P + 256*64)

#define BARR(g) (64 + (g) * 16)
#define BGRP    32
#define BREL(g) (512 + (g) * 16)

typedef float f4v __attribute__((ext_vector_type(4)));

// h loads: PLAIN CACHED 16B loads (batched; merged in per-XCD L2 -> 8x less
// fabric traffic than r12's sc0sc1 bypass reads). Freshness guaranteed by the
// once-per-step acquire fence (L1/L2 invalidate) in the grid barrier.
__device__ __forceinline__ void ld16(f4v* dst, const f4v* addr) {
  asm volatile("global_load_dwordx4 %0, %1, off" : "=v"(*dst) : "v"(addr));
}
// h stores: write-through to the coherence point (L3 always fresh; no dirty
// L2 lines anywhere -> acquire-invalidate is cheap, no writeback needed).
__device__ __forceinline__ void coh_st4(float* addr, float v) {
  asm volatile("global_store_dword %0, %1, off sc0 sc1" :: "v"(addr), "v"(v) : "memory");
}
#define VMWAIT(n) do { asm volatile("s_waitcnt vmcnt(" #n ")" ::: "memory"); \
                       __builtin_amdgcn_sched_barrier(0); } while (0)

// Two-level grid barrier (16 groups x 16), counters zeroed by prep. All
// probes are atomic RMWs (coherence point). Release->acquire: after the spin
// completes, ONE agent-scope acquire fence invalidates stale L1/L2 h lines.
__device__ __forceinline__ void grid_barrier(unsigned* bar, unsigned target, int tid, int bid) {
  asm volatile("s_waitcnt vmcnt(0)" ::: "memory");   // drain asm h-stores (all waves)
  __syncthreads();
  if (tid == 0) {
    const unsigned g = (unsigned)bid & 15u;
    const unsigned o = atomicAdd(&bar[BARR(g)], 1u);
    if ((o & 15u) == 15u) {
      const unsigned o2 = atomicAdd(&bar[BGRP], 1u);
      if ((o2 & 15u) == 15u) {
#pragma unroll
        for (int q = 0; q < 16; ++q) atomicExch(&bar[BREL(q)], target);
      }
    }
    unsigned spins = 0;
    while (atomicAdd(&bar[BREL(g)], 0u) != target) {
      if (++spins > 30000u) break;                   // safety net
      __builtin_amdgcn_s_sleep(2);
    }
  }
  __syncthreads();
  __builtin_amdgcn_fence(__ATOMIC_ACQUIRE, "agent"); // invalidate stale L1/L2
}

// One LSTM layer phase (r12 structure). Block owns unit pair p => 8 gate
// cols. 8 waves k-split. h: batched cached quad loads (16 issued, 1 wait).
// Weights: LDS wave-uniform broadcast. Accuracy: 32-term f32 fma chains +
// f64 accumulation -- summation order identical to rounds 5-13.
__device__ __forceinline__ void lstm_phase(
    int l0flag, int Ktot, const float* wsec,
    const float* belowT, const float* ownT,
    const float br[4], float* hdstT, float* creg,
    const int* __restrict__ tokens, const float* __restrict__ emb,
    const float* w0l, int t,
    double* dz, int p, int tid)
{
  const int lane = tid & 63;                                  // batch row m
  const int w = __builtin_amdgcn_readfirstlane(tid >> 6);     // wave 0..7 -> SGPR
  const int Kq = Ktot >> 3;                                   // 64 or 128
  const int k0 = w * Kq;
  const float* hsrc = (Ktot == 512 || w < 4) ? belowT : ownT; // wave-uniform
  const int kbase = (Ktot == 512 || w < 4) ? k0 : k0 - 512;
  const f4v* hq = (const f4v*)hsrc;
  const int nch = Kq >> 6;                                    // 1 or 2 chunks
  double d[8] = {0.0, 0.0, 0.0, 0.0, 0.0, 0.0, 0.0, 0.0};

  for (int ch = 0; ch < nch; ++ch) {
    const int kq0 = (kbase >> 2) + ch * 16;
    f4v h[16];
#pragma unroll
    for (int i = 0; i < 16; ++i)                              // issue 16 loads
      ld16(&h[i], hq + (size_t)(kq0 + i) * 64 + lane);
    VMWAIT(0);                                                // one wait
#pragma unroll
    for (int g2 = 0; g2 < 2; ++g2) {                          // two 32-k chains
      float s8[8] = {0.f, 0.f, 0.f, 0.f, 0.f, 0.f, 0.f, 0.f};
#pragma unroll
      for (int i = 0; i < 8; ++i) {
        const f4v hv = h[g2 * 8 + i];
#pragma unroll
        for (int q = 0; q < 4; ++q) {
          const float xk = hv[q];
          const int kl = k0 + ch * 64 + g2 * 32 + i * 4 + q;
          const float4 wa = *(const float4*)&wsec[(size_t)kl * 8];     // LDS bcast
          const float4 wb = *(const float4*)&wsec[(size_t)kl * 8 + 4];
          s8[0] = fmaf(xk, wa.x, s8[0]); s8[1] = fmaf(xk, wa.y, s8[1]);
          s8[2] = fmaf(xk, wa.z, s8[2]); s8[3] = fmaf(xk, wa.w, s8[3]);
          s8[4] = fmaf(xk, wb.x, s8[4]); s8[5] = fmaf(xk, wb.y, s8[5]);
          s8[6] = fmaf(xk, wb.z, s8[6]); s8[7] = fmaf(xk, wb.w, s8[7]);
        }
      }
#pragma unroll
      for (int j = 0; j < 8; ++j) d[j] += (double)s8[j];      // per-32k f64 flush
    }
  }

  if (l0flag && w == 0) {                  // embedding K=8 part (once, wave 0)
    const int tok = tokens[lane * TT + t];
    float s8[8] = {0.f, 0.f, 0.f, 0.f, 0.f, 0.f, 0.f, 0.f};
#pragma unroll
    for (int e = 0; e < 8; ++e) {
      const float xe = emb[tok * 8 + e];
      const float4 wa = *(const float4*)&w0l[e * 8];
      const float4 wb = *(const float4*)&w0l[e * 8 + 4];
      s8[0] = fmaf(xe, wa.x, s8[0]); s8[1] = fmaf(xe, wa.y, s8[1]);
      s8[2] = fmaf(xe, wa.z, s8[2]); s8[3] = fmaf(xe, wa.w, s8[3]);
      s8[4] = fmaf(xe, wb.x, s8[4]); s8[5] = fmaf(xe, wb.y, s8[5]);
      s8[6] = fmaf(xe, wb.z, s8[6]); s8[7] = fmaf(xe, wb.w, s8[7]);
    }
#pragma unroll
    for (int j = 0; j < 8; ++j) d[j] += (double)s8[j];
  }

#pragma unroll
  for (int j = 0; j < 8; ++j) dz[(j * 8 + w) * DZP + lane] = d[j];
  __syncthreads();

  if (tid < 128) {
    const int m = tid & 63, uu = tid >> 6;
    float zf[4];
#pragma unroll
    for (int g = 0; g < 4; ++g) {
      double zs = (double)br[g];
#pragma unroll
      for (int w8 = 0; w8 < 8; ++w8)
        zs += dz[((g * 2 + uu) * 8 + w8) * DZP + m];
      zf[g] = (float)zs;
    }
    const float iv = 1.f / (1.f + expf(-zf[0]));
    const float fv = 1.f / (1.f + expf(-zf[1]));
    const float gv = tanhf(zf[2]);
    const float ov = 1.f / (1.f + expf(-zf[3]));
    const float cn = fv * (*creg) + iv * gv;       // c lives in a register
    *creg = cn;
    const int u = 2 * p + uu;
    coh_st4(&hdstT[((u >> 2) * 64 + m) * 4 + (u & 3)], ov * tanhf(cn));
  }
  __syncthreads();                                 // dz safe for next phase
}

__global__ void __launch_bounds__(256)
rnn_prep(float* __restrict__ ws,
         const float* __restrict__ W0, const float* __restrict__ U0,
         const float* __restrict__ W1, const float* __restrict__ U1,
         const float* __restrict__ W2, const float* __restrict__ U2)
{
  const int tid = (int)threadIdx.x;
  const int bid = (int)blockIdx.x;
  const int gtid = bid * 256 + tid;
  for (int i = gtid; i < WS_ZERO; i += 768 * 256) ws[i] = 0.f;  // bar + h zeroed

  float* CWP0 = ws + O_CWP0;
  float* CWP1 = ws + O_CWP1;
  float* CWP2 = ws + O_CWP2;
  float* W0P  = ws + O_W0P;
  if (bid < 256) {
    const int p = bid;
    for (int k = tid; k < 512; k += 256)
#pragma unroll
      for (int j = 0; j < 8; ++j) {
        const int col = ((j >> 1) << 9) + 2 * p + (j & 1);
        CWP0[((size_t)p * 512 + k) * 8 + j] = U0[(size_t)k * 2048 + col];
      }
    if (tid < 64) {
      const int e = tid >> 3, j = tid & 7;
      const int col = ((j >> 1) << 9) + 2 * p + (j & 1);
      W0P[p * 64 + e * 8 + j] = W0[(size_t)e * 2048 + col];
    }
  } else if (bid < 512) {
    const int p = bid - 256;
    for (int k = tid; k < 1024; k += 256) {
      const float* src = (k < 512) ? &W1[(size_t)k * 2048] : &U1[(size_t)(k - 512) * 2048];
#pragma unroll
      for (int j = 0; j < 8; ++j) {
        const int col = ((j >> 1) << 9) + 2 * p + (j & 1);
        CWP1[((size_t)p * 1024 + k) * 8 + j] = src[col];
      }
    }
  } else {
    const int p = bid - 512;
    for (int k = tid; k < 1024; k += 256) {
      const float* src = (k < 512) ? &W2[(size_t)k * 2048] : &U2[(size_t)(k - 512) * 2048];
#pragma unroll
      for (int j = 0; j < 8; ++j) {
        const int col = ((j >> 1) << 9) + 2 * p + (j & 1);
        CWP2[((size_t)p * 1024 + k) * 8 + j] = src[col];
      }
    }
  }
}

__global__ void __launch_bounds__(512, 1)
rnn_all(const int* __restrict__ tokens, const float* __restrict__ emb,
        const float* __restrict__ b0, const float* __restrict__ b1,
        const float* __restrict__ b2,
        const float* __restrict__ Wd, const float* __restrict__ bd,
        float* __restrict__ out, float* __restrict__ ws)
{
  __shared__ __align__(16) float wl[20544];    // 80.25 KiB weight slice
  __shared__ double dz[64 * DZP];              // 33.3 KiB partials (padded)
  __shared__ float red[512];                   // 2 KiB softmax reduce
  const int tid = (int)threadIdx.x;
  const int p = (int)blockIdx.x;               // unit pair
  unsigned* bar = (unsigned*)ws;
  float* ht = ws + O_HT;

  { // one-time LDS weight load (broadcast-read thereafter; no refetch ever)
    const float* s0 = ws + O_CWP0 + (size_t)p * 4096;
    for (int i = tid; i < 4096; i += 512) wl[i] = s0[i];
    const float* s1 = ws + O_CWP1 + (size_t)p * 8192;
    for (int i = tid; i < 8192; i += 512) wl[4096 + i] = s1[i];
    const float* s2 = ws + O_CWP2 + (size_t)p * 8192;
    for (int i = tid; i < 8192; i += 512) wl[12288 + i] = s2[i];
    if (tid < 64) wl[20480 + tid] = ws[O_W0P + p * 64 + tid];
  }
  // preload per-thread bias/bd registers (avoids post-invalidate refetch
  // latency in the epilogue / FIN paths)
  float br0[4], br1[4], br2[4], bdr;
  {
    const int uu = (tid >> 6) & 1;
#pragma unroll
    for (int g = 0; g < 4; ++g) {
      const int c_ = (g << 9) + 2 * p + uu;
      br0[g] = b0[c_]; br1[g] = b1[c_]; br2[g] = b2[c_];
    }
    bdr = bd[tid & 127];
  }
  float c0 = 0.f, c1 = 0.f, c2 = 0.f;          // cell state in registers
  __syncthreads();

  for (int s = 0; s < 515; ++s) {
    const int po = (s + 1) & 1;                // parity of prev-superstep outputs
    const int pw = s & 1;                      // parity written this superstep
    float* h0po = ht + (size_t)(0 * 2 + po) * 32768;
    float* h1po = ht + (size_t)(1 * 2 + po) * 32768;
    float* h2po = ht + (size_t)(2 * 2 + po) * 32768;
    float* h0pw = ht + (size_t)(0 * 2 + pw) * 32768;
    float* h1pw = ht + (size_t)(1 * 2 + pw) * 32768;
    float* h2pw = ht + (size_t)(2 * 2 + pw) * 32768;

    if (s < 512)                               // L0: t=s (K=512 recurrent + emb)
      lstm_phase(1, 512, wl, h0po, h0po, br0, h0pw, &c0, tokens, emb,
                 wl + 20480, s, dz, p, tid);
    if (s >= 1 && s < 513)                     // L1: t=s-1
      lstm_phase(0, 1024, wl + 4096, h0po, h1po, br1, h1pw, &c1,
                 nullptr, nullptr, nullptr, 0, dz, p, tid);
    if (s >= 2 && s < 514)                     // L2: t=s-2
      lstm_phase(0, 1024, wl + 12288, h1po, h2po, br2, h2pw, &c2,
                 nullptr, nullptr, nullptr, 0, dz, p, tid);

    if (s >= 3 && p < 64) {                    // FIN: logits+softmax, t=s-3, row p
      const int r = p;
      const f4v* h2q = (const f4v*)h2po;
      const int col = tid & 127, kq4 = tid >> 7;
      double acc = 0.0;
      for (int ch = 0; ch < 4; ++ch) {
        f4v h[8];
#pragma unroll
        for (int i = 0; i < 8; ++i)
          ld16(&h[i], h2q + (size_t)(kq4 * 32 + ch * 8 + i) * 64 + r);
        VMWAIT(0);
        float sa = 0.f;
#pragma unroll
        for (int i = 0; i < 8; ++i)
#pragma unroll
          for (int q = 0; q < 4; ++q) {
            const int k = (kq4 * 32 + ch * 8 + i) * 4 + q;
            sa = fmaf(h[i][q], Wd[(size_t)k * 128 + col], sa);
          }
        acc += (double)sa;
      }
      dz[tid] = acc;
      __syncthreads();
      float xlg = -3.0e38f;
      if (tid < 128)
        xlg = (float)(dz[tid] + dz[tid + 128] + dz[tid + 256] + dz[tid + 384]
                      + (double)bdr);
      red[tid] = xlg;                       __syncthreads();
      if (tid < 256) red[tid] = fmaxf(red[tid], red[tid + 256]); __syncthreads();
      if (tid < 128) red[tid] = fmaxf(red[tid], red[tid + 128]); __syncthreads();
      if (tid < 64)  red[tid] = fmaxf(red[tid], red[tid + 64]);  __syncthreads();
      if (tid < 32)  red[tid] = fmaxf(red[tid], red[tid + 32]);  __syncthreads();
      if (tid < 16)  red[tid] = fmaxf(red[tid], red[tid + 16]);  __syncthreads();
      if (tid < 8)   red[tid] = fmaxf(red[tid], red[tid + 8]);   __syncthreads();
      if (tid < 4)   red[tid] = fmaxf(red[tid], red[tid + 4]);   __syncthreads();
      if (tid < 2)   red[tid] = fmaxf(red[tid], red[tid + 2]);   __syncthreads();
      if (tid < 1)   red[tid] = fmaxf(red[tid], red[tid + 1]);   __syncthreads();
      const float mx = red[0];              __syncthreads();
      const float ex = (tid < 128) ? expf(xlg - mx) : 0.f;
      red[tid] = ex;                        __syncthreads();
      if (tid < 256) red[tid] += red[tid + 256]; __syncthreads();
      if (tid < 128) red[tid] += red[tid + 128]; __syncthreads();
      if (tid < 64)  red[tid] += red[tid + 64];  __syncthreads();
      if (tid < 32)  red[tid] += red[tid + 32];  __syncthreads();
      if (tid < 16)  red[tid] += red[tid + 16];  __syncthreads();
      if (tid < 8)   red[tid] += red[tid + 8];   __syncthreads();
      if (tid < 4)   red[tid] += red[tid + 4];   __syncthreads();
      if (tid < 2)   red[tid] += red[tid + 2];   __syncthreads();
      if (tid < 1)   red[tid] += red[tid + 1];   __syncthreads();
      const float inv = 1.f / red[0];
      if (tid < 128) out[((size_t)r * 512 + (s - 3)) * 128 + tid] = ex * inv;
    }

    grid_barrier(bar, (unsigned)(s + 1), tid, p);
  }
}

extern "C" void kernel_launch(void* const* d_in, const int* in_sizes, int n_in,
                              void* d_out, int out_size, void* d_ws, size_t ws_size,
                              hipStream_t stream) {
  (void)in_sizes; (void)n_in; (void)out_size;
  if (ws_size < (size_t)WS_ALL * 4) return;    // 21.8 MB, proven available
  const int*   tokens = (const int*)d_in[0];
  const float* emb = (const float*)d_in[1];
  const float* W0 = (const float*)d_in[2];
  const float* U0 = (const float*)d_in[3];
  const float* b0 = (const float*)d_in[4];
  const float* W1 = (const float*)d_in[5];
  const float* U1 = (const float*)d_in[6];
  const float* b1 = (const float*)d_in[7];
  const float* W2 = (const float*)d_in[8];
  const float* U2 = (const float*)d_in[9];
  const float* b2 = (const float*)d_in[10];
  const float* Wd = (const float*)d_in[11];
  const float* bd = (const float*)d_in[12];
  float* out = (float*)d_out;
  float* ws  = (float*)d_ws;

  hipLaunchKernelGGL(rnn_prep, dim3(768), dim3(256), 0, stream,
                     ws, W0, U0, W1, U1, W2, U2);
  hipLaunchKernelGGL(rnn_all, dim3(256), dim3(512), 0, stream,
                     tokens, emb, b0, b1, b2, Wd, bd, out, ws);
}

// Round 15
// 13154.318 us; speedup vs baseline: 2.2088x; 1.6708x over previous
//
#include <hip/hip_runtime.h>
#include <cstdint>
#include <cstddef>

#define TT 512
#define DZP 65                              // dz row stride (doubles), conflict-free

// ---- ws layout (float offsets) ----  total ~22.1 MB
#define O_BAR   0                           // 1024 barrier words (zeroed by prep)
#define O_HT    1024                        // [3 layer][2 parity] hq[128 kq][64 m][4 q]
#define O_PLGB  (O_HT + 6*32768)            // [2 par][4 q][64 r][128] logit partials
#define WS_ZERO (O_PLGB + 2*32768)          // prep zeroes [0, WS_ZERO)
#define O_CWP0  WS_ZERO                     // [256 p][512 k][8 j]   U0 packed
#define O_CWP1  (O_CWP0 + 256*512*8)        // [256 p][1024 k][8 j]  [W1;U1] packed
#define O_CWP2  (O_CWP1 + 256*1024*8)       // [256 p][1024 k][8 j]  [W2;U2] packed
#define O_W0P   (O_CWP2 + 256*1024*8)       // [256 p][8 e][8 j]     W0 packed
#define WS_ALL  (O_W0P + 256*64)

#define BARR(g) (64 + (g) * 16)
#define BGRP    32
#define BREL(g) (512 + (g) * 16)

typedef float f4v __attribute__((ext_vector_type(4)));

// Coherent (cross-XCD) ops: plain global instrs with sc0+sc1 — bypass stale
// L1/L2, served at the coherence point; batchable, counted by vmcnt.
// (r14 showed cached-reads + per-step invalidate is WORSE than this.)
__device__ __forceinline__ void coh_ld16(f4v* dst, const f4v* addr) {
  asm volatile("global_load_dwordx4 %0, %1, off sc0 sc1" : "=v"(*dst) : "v"(addr));
}
__device__ __forceinline__ void coh_ld4(float* dst, const float* addr) {
  asm volatile("global_load_dword %0, %1, off sc0 sc1" : "=v"(*dst) : "v"(addr));
}
__device__ __forceinline__ void coh_st4(float* addr, float v) {
  asm volatile("global_store_dword %0, %1, off sc0 sc1" :: "v"(addr), "v"(v) : "memory");
}
#define VMWAIT(n) do { asm volatile("s_waitcnt vmcnt(" #n ")" ::: "memory"); \
                       __builtin_amdgcn_sched_barrier(0); } while (0)

// Two-level grid barrier (16 groups x 16), counters zeroed by prep. All
// probes are atomic RMWs. Every wave drains vmcnt(0) first (coherent h /
// partial stores must be at the coherence point before arrival).
__device__ __forceinline__ void grid_barrier(unsigned* bar, unsigned target, int tid, int bid) {
  asm volatile("s_waitcnt vmcnt(0)" ::: "memory");
  __syncthreads();
  if (tid == 0) {
    const unsigned g = (unsigned)bid & 15u;
    const unsigned o = atomicAdd(&bar[BARR(g)], 1u);
    if ((o & 15u) == 15u) {
      const unsigned o2 = atomicAdd(&bar[BGRP], 1u);
      if ((o2 & 15u) == 15u) {
#pragma unroll
        for (int q = 0; q < 16; ++q) atomicExch(&bar[BREL(q)], target);
      }
    }
    unsigned spins = 0;
    while (atomicAdd(&bar[BREL(g)], 0u) != target) {
      if (++spins > 30000u) break;                   // safety net
      __builtin_amdgcn_s_sleep(2);
    }
  }
  __syncthreads();
}

__device__ __forceinline__ void issue8(f4v h[8], const f4v* hq, int kq0, int lane) {
  const f4v* base = hq + (size_t)kq0 * 64 + lane;
#pragma unroll
  for (int i = 0; i < 8; ++i) coh_ld16(&h[i], base + i * 64);
}

// one 32-k chunk: f32 fma chain per gate col + one f64 flush (order = r12)
__device__ __forceinline__ void comp32(const f4v h[8], const float* wk, double d[8]) {
  float s8[8] = {0.f, 0.f, 0.f, 0.f, 0.f, 0.f, 0.f, 0.f};
#pragma unroll
  for (int i = 0; i < 8; ++i) {
#pragma unroll
    for (int q = 0; q < 4; ++q) {
      const float xk = h[i][q];
      const float4 wa = *(const float4*)&wk[(i * 4 + q) * 8];      // LDS bcast
      const float4 wb = *(const float4*)&wk[(i * 4 + q) * 8 + 4];
      s8[0] = fmaf(xk, wa.x, s8[0]); s8[1] = fmaf(xk, wa.y, s8[1]);
      s8[2] = fmaf(xk, wa.z, s8[2]); s8[3] = fmaf(xk, wa.w, s8[3]);
      s8[4] = fmaf(xk, wb.x, s8[4]); s8[5] = fmaf(xk, wb.y, s8[5]);
      s8[6] = fmaf(xk, wb.z, s8[6]); s8[7] = fmaf(xk, wb.w, s8[7]);
    }
  }
#pragma unroll
  for (int j = 0; j < 8; ++j) d[j] += (double)s8[j];
}

// One LSTM layer phase (r12 structure + counted waits). Block owns unit pair
// p => 8 gate cols. 8 waves k-split. Weights: LDS broadcast. h: coherent
// quad loads, 32 issued, vmcnt(16)/vmcnt(0) counted waits.
__device__ __forceinline__ void lstm_phase(
    int l0flag, int Ktot, const float* wsec,
    const float* belowT, const float* ownT,
    const float br[4], float* hdstT, float* creg,
    const int* __restrict__ tokens, const float* __restrict__ emb,
    const float* w0l, int t,
    double* dz, int p, int tid)
{
  const int lane = tid & 63;                                  // batch row m
  const int w = __builtin_amdgcn_readfirstlane(tid >> 6);     // wave 0..7 -> SGPR
  const int Kq = Ktot >> 3;                                   // 64 or 128
  const int k0 = w * Kq;
  const float* hsrc = (Ktot == 512 || w < 4) ? belowT : ownT; // wave-uniform
  const int kbase = (Ktot == 512 || w < 4) ? k0 : k0 - 512;
  const f4v* hq = (const f4v*)hsrc;
  const int kq0 = kbase >> 2;
  double d[8] = {0.0, 0.0, 0.0, 0.0, 0.0, 0.0, 0.0, 0.0};

  if (Ktot == 512) {
    f4v hA[8], hB[8];
    issue8(hA, hq, kq0, lane); issue8(hB, hq, kq0 + 8, lane);
    VMWAIT(8);  comp32(hA, wsec + (size_t)k0 * 8, d);
    VMWAIT(0);  comp32(hB, wsec + (size_t)(k0 + 32) * 8, d);
  } else {
    f4v hA[8], hB[8], hC[8], hD[8];
    issue8(hA, hq, kq0, lane);      issue8(hB, hq, kq0 + 8, lane);
    issue8(hC, hq, kq0 + 16, lane); issue8(hD, hq, kq0 + 24, lane);
    VMWAIT(16);
    comp32(hA, wsec + (size_t)k0 * 8, d);
    comp32(hB, wsec + (size_t)(k0 + 32) * 8, d);
    VMWAIT(0);
    comp32(hC, wsec + (size_t)(k0 + 64) * 8, d);
    comp32(hD, wsec + (size_t)(k0 + 96) * 8, d);
  }

  if (l0flag && w == 0) {                  // embedding K=8 part (once, wave 0)
    const int tok = tokens[lane * TT + t];
    float s8[8] = {0.f, 0.f, 0.f, 0.f, 0.f, 0.f, 0.f, 0.f};
#pragma unroll
    for (int e = 0; e < 8; ++e) {
      const float xe = emb[tok * 8 + e];
      const float4 wa = *(const float4*)&w0l[e * 8];
      const float4 wb = *(const float4*)&w0l[e * 8 + 4];
      s8[0] = fmaf(xe, wa.x, s8[0]); s8[1] = fmaf(xe, wa.y, s8[1]);
      s8[2] = fmaf(xe, wa.z, s8[2]); s8[3] = fmaf(xe, wa.w, s8[3]);
      s8[4] = fmaf(xe, wb.x, s8[4]); s8[5] = fmaf(xe, wb.y, s8[5]);
      s8[6] = fmaf(xe, wb.z, s8[6]); s8[7] = fmaf(xe, wb.w, s8[7]);
    }
#pragma unroll
    for (int j = 0; j < 8; ++j) d[j] += (double)s8[j];
  }

#pragma unroll
  for (int j = 0; j < 8; ++j) dz[(j * 8 + w) * DZP + lane] = d[j];
  __syncthreads();

  if (tid < 128) {
    const int m = tid & 63, uu = tid >> 6;
    float zf[4];
#pragma unroll
    for (int g = 0; g < 4; ++g) {
      double zs = (double)br[g];
#pragma unroll
      for (int w8 = 0; w8 < 8; ++w8)
        zs += dz[((g * 2 + uu) * 8 + w8) * DZP + m];
      zf[g] = (float)zs;
    }
    const float iv = 1.f / (1.f + expf(-zf[0]));
    const float fv = 1.f / (1.f + expf(-zf[1]));
    const float gv = tanhf(zf[2]);
    const float ov = 1.f / (1.f + expf(-zf[3]));
    const float cn = fv * (*creg) + iv * gv;       // c lives in a register
    *creg = cn;
    const int u = 2 * p + uu;
    coh_st4(&hdstT[((u >> 2) * 64 + m) * 4 + (u & 3)], ov * tanhf(cn));
  }
  __syncthreads();                                 // dz safe for next phase
}

__global__ void __launch_bounds__(256)
rnn_prep(float* __restrict__ ws,
         const float* __restrict__ W0, const float* __restrict__ U0,
         const float* __restrict__ W1, const float* __restrict__ U1,
         const float* __restrict__ W2, const float* __restrict__ U2)
{
  const int tid = (int)threadIdx.x;
  const int bid = (int)blockIdx.x;
  const int gtid = bid * 256 + tid;
  for (int i = gtid; i < WS_ZERO; i += 768 * 256) ws[i] = 0.f;  // bar+h+plgb

  float* CWP0 = ws + O_CWP0;
  float* CWP1 = ws + O_CWP1;
  float* CWP2 = ws + O_CWP2;
  float* W0P  = ws + O_W0P;
  if (bid < 256) {
    const int p = bid;
    for (int k = tid; k < 512; k += 256)
#pragma unroll
      for (int j = 0; j < 8; ++j) {
        const int col = ((j >> 1) << 9) + 2 * p + (j & 1);
        CWP0[((size_t)p * 512 + k) * 8 + j] = U0[(size_t)k * 2048 + col];
      }
    if (tid < 64) {
      const int e = tid >> 3, j = tid & 7;
      const int col = ((j >> 1) << 9) + 2 * p + (j & 1);
      W0P[p * 64 + e * 8 + j] = W0[(size_t)e * 2048 + col];
    }
  } else if (bid < 512) {
    const int p = bid - 256;
    for (int k = tid; k < 1024; k += 256) {
      const float* src = (k < 512) ? &W1[(size_t)k * 2048] : &U1[(size_t)(k - 512) * 2048];
#pragma unroll
      for (int j = 0; j < 8; ++j) {
        const int col = ((j >> 1) << 9) + 2 * p + (j & 1);
        CWP1[((size_t)p * 1024 + k) * 8 + j] = src[col];
      }
    }
  } else {
    const int p = bid - 512;
    for (int k = tid; k < 1024; k += 256) {
      const float* src = (k < 512) ? &W2[(size_t)k * 2048] : &U2[(size_t)(k - 512) * 2048];
#pragma unroll
      for (int j = 0; j < 8; ++j) {
        const int col = ((j >> 1) << 9) + 2 * p + (j & 1);
        CWP2[((size_t)p * 1024 + k) * 8 + j] = src[col];
      }
    }
  }
}

__global__ void __launch_bounds__(512, 1)
rnn_all(const int* __restrict__ tokens, const float* __restrict__ emb,
        const float* __restrict__ b0, const float* __restrict__ b1,
        const float* __restrict__ b2,
        const float* __restrict__ Wd, const float* __restrict__ bd,
        float* __restrict__ out, float* __restrict__ ws)
{
  __shared__ __align__(16) float wl[20544];    // 80.25 KiB weight slice
  __shared__ double dz[64 * DZP];              // 33.3 KiB partials (padded)
  __shared__ float red[512];                   // 2 KiB softmax reduce
  const int tid = (int)threadIdx.x;
  const int p = (int)blockIdx.x;               // unit pair / FIN (row, quarter)
  unsigned* bar = (unsigned*)ws;
  float* ht = ws + O_HT;
  float* plgb = ws + O_PLGB;

  { // one-time LDS weight load (broadcast-read thereafter; no refetch ever)
    const float* s0 = ws + O_CWP0 + (size_t)p * 4096;
    for (int i = tid; i < 4096; i += 512) wl[i] = s0[i];
    const float* s1 = ws + O_CWP1 + (size_t)p * 8192;
    for (int i = tid; i < 8192; i += 512) wl[4096 + i] = s1[i];
    const float* s2 = ws + O_CWP2 + (size_t)p * 8192;
    for (int i = tid; i < 8192; i += 512) wl[12288 + i] = s2[i];
    if (tid < 64) wl[20480 + tid] = ws[O_W0P + p * 64 + tid];
  }
  float br0[4], br1[4], br2[4], bdr;           // preloaded bias registers
  {
    const int uu = (tid >> 6) & 1;
#pragma unroll
    for (int g = 0; g < 4; ++g) {
      const int c_ = (g << 9) + 2 * p + uu;
      br0[g] = b0[c_]; br1[g] = b1[c_]; br2[g] = b2[c_];
    }
    bdr = bd[tid & 127];
  }
  float c0 = 0.f, c1 = 0.f, c2 = 0.f;          // cell state in registers
  __syncthreads();

  for (int s = 0; s < 516; ++s) {
    const int po = (s + 1) & 1;                // parity of prev-superstep outputs
    const int pw = s & 1;                      // parity written this superstep
    float* h0po = ht + (size_t)(0 * 2 + po) * 32768;
    float* h1po = ht + (size_t)(1 * 2 + po) * 32768;
    float* h2po = ht + (size_t)(2 * 2 + po) * 32768;
    float* h0pw = ht + (size_t)(0 * 2 + pw) * 32768;
    float* h1pw = ht + (size_t)(1 * 2 + pw) * 32768;
    float* h2pw = ht + (size_t)(2 * 2 + pw) * 32768;

    if (s < 512)                               // L0: t=s (K=512 recurrent + emb)
      lstm_phase(1, 512, wl, h0po, h0po, br0, h0pw, &c0, tokens, emb,
                 wl + 20480, s, dz, p, tid);
    if (s >= 1 && s < 513)                     // L1: t=s-1
      lstm_phase(0, 1024, wl + 4096, h0po, h1po, br1, h1pw, &c1,
                 nullptr, nullptr, nullptr, 0, dz, p, tid);
    if (s >= 2 && s < 514)                     // L2: t=s-2
      lstm_phase(0, 1024, wl + 12288, h1po, h2po, br2, h2pw, &c2,
                 nullptr, nullptr, nullptr, 0, dz, p, tid);

    if (s >= 3 && s < 515) {                   // FINP: logit partials, t=s-3
      const int r = p & 63, q = p >> 6;        // ALL 256 blocks: (row, k-quarter)
      const f4v* h2q = (const f4v*)h2po;
      const int col = tid & 127, ks = tid >> 7;
      const int kqb = q * 32 + ks * 8;
      f4v h[8];
#pragma unroll
      for (int i = 0; i < 8; ++i)              // wave-broadcast (uniform addr)
        coh_ld16(&h[i], h2q + (size_t)(kqb + i) * 64 + r);
      VMWAIT(0);
      float sa = 0.f;
#pragma unroll
      for (int i = 0; i < 8; ++i)
#pragma unroll
        for (int qq = 0; qq < 4; ++qq) {
          const int k = (kqb + i) * 4 + qq;
          sa = fmaf(h[i][qq], Wd[(size_t)k * 128 + col], sa);
        }
      dz[tid] = (double)sa;
      __syncthreads();
      if (tid < 128) {
        const double psum = dz[tid] + dz[tid + 128] + dz[tid + 256] + dz[tid + 384];
        coh_st4(&plgb[(size_t)pw * 32768 + q * 8192 + r * 128 + tid], (float)psum);
      }
      __syncthreads();                         // dz free again
    }

    if (s >= 4 && p < 64) {                    // FINS: softmax+store, t=s-4, row p
      float p0, p1, p2, p3;
      float xlg = -3.0e38f;
      if (tid < 128) {
        const float* pb = plgb + (size_t)po * 32768 + p * 128 + tid;
        coh_ld4(&p0, pb);          coh_ld4(&p1, pb + 8192);
        coh_ld4(&p2, pb + 16384);  coh_ld4(&p3, pb + 24576);
        VMWAIT(0);
        xlg = (float)(((double)p0 + (double)p1 + (double)p2 + (double)p3)
                      + (double)bdr);
      }
      red[tid] = xlg;                       __syncthreads();
      if (tid < 256) red[tid] = fmaxf(red[tid], red[tid + 256]); __syncthreads();
      if (tid < 128) red[tid] = fmaxf(red[tid], red[tid + 128]); __syncthreads();
      if (tid < 64)  red[tid] = fmaxf(red[tid], red[tid + 64]);  __syncthreads();
      if (tid < 32)  red[tid] = fmaxf(red[tid], red[tid + 32]);  __syncthreads();
      if (tid < 16)  red[tid] = fmaxf(red[tid], red[tid + 16]);  __syncthreads();
      if (tid < 8)   red[tid] = fmaxf(red[tid], red[tid + 8]);   __syncthreads();
      if (tid < 4)   red[tid] = fmaxf(red[tid], red[tid + 4]);   __syncthreads();
      if (tid < 2)   red[tid] = fmaxf(red[tid], red[tid + 2]);   __syncthreads();
      if (tid < 1)   red[tid] = fmaxf(red[tid], red[tid + 1]);   __syncthreads();
      const float mx = red[0];              __syncthreads();
      const float ex = (tid < 128) ? expf(xlg - mx) : 0.f;
      red[tid] = ex;                        __syncthreads();
      if (tid < 256) red[tid] += red[tid + 256]; __syncthreads();
      if (tid < 128) red[tid] += red[tid + 128]; __syncthreads();
      if (tid < 64)  red[tid] += red[tid + 64];  __syncthreads();
      if (tid < 32)  red[tid] += red[tid + 32];  __syncthreads();
      if (tid < 16)  red[tid] += red[tid + 16];  __syncthreads();
      if (tid < 8)   red[tid] += red[tid + 8];   __syncthreads();
      if (tid < 4)   red[tid] += red[tid + 4];   __syncthreads();
      if (tid < 2)   red[tid] += red[tid + 2];   __syncthreads();
      if (tid < 1)   red[tid] += red[tid + 1];   __syncthreads();
      const float inv = 1.f / red[0];
      if (tid < 128) out[((size_t)p * 512 + (s - 4)) * 128 + tid] = ex * inv;
    }

    grid_barrier(bar, (unsigned)(s + 1), tid, p);
  }
}

extern "C" void kernel_launch(void* const* d_in, const int* in_sizes, int n_in,
                              void* d_out, int out_size, void* d_ws, size_t ws_size,
                              hipStream_t stream) {
  (void)in_sizes; (void)n_in; (void)out_size;
  if (ws_size < (size_t)WS_ALL * 4) return;    // ~22.1 MB (22.2 proven available)
  const int*   tokens = (const int*)d_in[0];
  const float* emb = (const float*)d_in[1];
  const float* W0 = (const float*)d_in[2];
  const float* U0 = (const float*)d_in[3];
  const float* b0 = (const float*)d_in[4];
  const float* W1 = (const float*)d_in[5];
  const float* U1 = (const float*)d_in[6];
  const float* b1 = (const float*)d_in[7];
  const float* W2 = (const float*)d_in[8];
  const float* U2 = (const float*)d_in[9];
  const float* b2 = (const float*)d_in[10];
  const float* Wd = (const float*)d_in[11];
  const float* bd = (const float*)d_in[12];
  float* out = (float*)d_out;
  float* ws  = (float*)d_ws;

  hipLaunchKernelGGL(rnn_prep, dim3(768), dim3(256), 0, stream,
                     ws, W0, U0, W1, U1, W2, U2);
  hipLaunchKernelGGL(rnn_all, dim3(256), dim3(512), 0, stream,
                     tokens, emb, b0, b1, b2, Wd, bd, out, ws);
}